// Round 7
// baseline (461.447 us; speedup 1.0000x reference)
//
#include <hip/hip_runtime.h>
#include <hip/hip_bf16.h>
#include <stdint.h>

// Problem constants (reference: N=16384, F=1024, B=512)
#define N_ROWS 16384
#define F_DIM  1024
#define B_DIM  512
#define K_DIM  1536   // F + B
#define G_DIM  4096   // 4*F
#define NT     24     // K_DIM / 64 K-tiles
#define CB_STR 68     // padded fp32 stride for epilogue LDS tile

typedef __bf16 v8bf __attribute__((ext_vector_type(8)));
typedef float  v4f  __attribute__((ext_vector_type(4)));

__device__ __forceinline__ unsigned short f2bf(float x) {
    union { float f; unsigned int u; } c; c.f = x;
    unsigned int u = c.u;
    return (unsigned short)((u + 0x7FFFu + ((u >> 16) & 1u)) >> 16);  // RNE; inputs finite
}

__device__ __forceinline__ float sigmoidf_fast(float x) {
    return 1.f / (1.f + __expf(-x));
}
__device__ __forceinline__ float tanhf_fast(float x) {
    return 1.f - 2.f / (__expf(2.f * x) + 1.f);   // saturates correctly at +/-1
}

// ---------------------------------------------------------------------------
// Merged pack kernel -> FRAGMENT-MAJOR layouts.
// A2 / W2 layout: [blk16][kchunk32][lane64][8 bf16], where a 16-row x 32-k
// subtile stores lane l = quad*16+lrow the 16B holding
// (row = blk*16+lrow, k = kc*32 + quad*8 .. +8). A wave's MFMA fragment load
// is then ONE coalesced 1KB global_load_dwordx4 at base + lane*16.
//   blocks [0, N_ROWS)           : A2 from [h_prev | behavior]
//   blocks [N_ROWS, N_ROWS+G_DIM): W2 gate-interleaved from [Wh | Wx], b'
// ---------------------------------------------------------------------------
__global__ void pack_all(const float* __restrict__ behavior,
                         const float* __restrict__ h_prev,
                         const float* __restrict__ Wh,
                         const float* __restrict__ Wx,
                         const float* __restrict__ b,
                         unsigned short* __restrict__ A2,
                         unsigned short* __restrict__ W2,
                         float* __restrict__ bperm) {
    const int blk = blockIdx.x;
    const int col = threadIdx.x * 8;              // 0..1528, never straddles 1024
    const float* src;
    unsigned short* dstbase;
    int row;
    if (blk < N_ROWS) {
        row = blk;
        src = (col < F_DIM) ? h_prev + (long)row * F_DIM + col
                            : behavior + (long)row * B_DIM + (col - F_DIM);
        dstbase = A2;
    } else {
        const int gp   = blk - N_ROWS;
        const int gate = gp & 3;
        const int f    = gp >> 2;
        const int g    = gate * F_DIM + f;        // original row in Wh/Wx
        row = gp;
        src = (col < F_DIM) ? Wh + (long)g * F_DIM + col
                            : Wx + (long)g * B_DIM + (col - F_DIM);
        dstbase = W2;
        if (threadIdx.x == 0) bperm[gp] = b[g];
    }
    float4 lo = *(const float4*)src;
    float4 hi = *(const float4*)(src + 4);
    union { unsigned short u[8]; int4 v; } p;
    p.u[0] = f2bf(lo.x); p.u[1] = f2bf(lo.y); p.u[2] = f2bf(lo.z); p.u[3] = f2bf(lo.w);
    p.u[4] = f2bf(hi.x); p.u[5] = f2bf(hi.y); p.u[6] = f2bf(hi.z); p.u[7] = f2bf(hi.w);
    // fragment-major destination
    const int kc   = col >> 5;
    const int quad = (col >> 3) & 3;
    const long off = ((long)(row >> 4) * 48 + kc) * 512 + (quad * 16 + (row & 15)) * 8;
    *(int4*)(dstbase + off) = p.v;
}

// ---------------------------------------------------------------------------
// Fused GEMM (gates = A @ W'^T) + bias + activations + c/h epilogue.
// 256x256 tile, BK=64, 8 waves (2Mx4N), 512 threads.
//
// LDS-FREE MAIN LOOP (r6 post-mortem: LDS port time ~2816 cyc/K-tile/CU vs
// MFMA 2483 -- co-critical; all staged schedules pinned at 33-36% MfmaUtil).
// Operands come straight global->VGPR via the fragment-major layouts above:
// per wave per K-tile 16 A-frag + 8 B-frag coalesced 1KB loads + 64 MFMA.
// Intra-CU reuse (A x4 waves, B x2) served by L1/L2. No barriers, no manual
// waitcnt: waves free-run; compiler inserts counted vmcnt before first use.
// Prefetch: B double-buffered one K-tile ahead (2 frags issued per quadrant);
// A alternates af0/af1 one quadrant ahead. Tail prefetch reads in-workspace
// garbage (verified in-bounds), discarded.
// ---------------------------------------------------------------------------
__global__ __launch_bounds__(512, 2) void lstm_gemm(
    const unsigned short* __restrict__ A2,  // fragment-major, 48 MB
    const unsigned short* __restrict__ W2,  // fragment-major, 12 MB
    const float* __restrict__ bperm,        // [G_DIM]
    const float* __restrict__ c_prev,       // [N_ROWS][F_DIM]
    float* __restrict__ out)                // [N_ROWS][F_DIM]
{
    extern __shared__ char smem[];          // 69632 B: epilogue cbuf only

    // Plain raster, n fastest (r4-measured best: FETCH 254 MB).
    const int bid = blockIdx.x;                   // 0..1023
    const int n0  = (bid & 15) << 8;              // gate-block * 256
    const int m0  = (bid >> 4) << 8;              // row-block * 256

    const int tid  = threadIdx.x;
    const int lane = tid & 63;
    const int wave = tid >> 6;
    const int wmi  = wave >> 2;                   // 0..1
    const int wni  = wave & 3;                    // 0..3
    const int lrow = lane & 15;
    const int quad = lane >> 4;

    // per-wave fragment base pointers (ushort units); frag (blkoff B, kc) at
    // base + B*24576 + kc*512
    const unsigned short* pA = A2 + ((long)((m0 >> 4) + wmi * 8) * 48) * 512 + lane * 8;
    const unsigned short* pB = W2 + ((long)((n0 >> 4) + wni * 4) * 48) * 512 + lane * 8;

    v4f acc[8][4] = {};                           // 128 fp32 accum / lane
    v8bf bfA[4][2], bfB[4][2];                    // B frags [nt][kh], cur/next
    v8bf af0[4], af1[4];                          // A quadrant frags [j*2+kh]

#define LDAQ(dst, kO, QQ)                                                       \
    dst[0] = *(const v8bf*)(pA + (kO) + ((QQ)*2    ) * 24576      );            \
    dst[1] = *(const v8bf*)(pA + (kO) + ((QQ)*2    ) * 24576 + 512);            \
    dst[2] = *(const v8bf*)(pA + (kO) + ((QQ)*2 + 1) * 24576      );            \
    dst[3] = *(const v8bf*)(pA + (kO) + ((QQ)*2 + 1) * 24576 + 512);

#define LDBF(dst, kO, NT)                                                       \
    dst[NT][0] = *(const v8bf*)(pB + (kO) + (NT) * 24576      );                \
    dst[NT][1] = *(const v8bf*)(pB + (kO) + (NT) * 24576 + 512);

#define MFMAQ(Q, AF, BF)                                                        \
    __builtin_amdgcn_s_setprio(1);                                              \
    _Pragma("unroll")                                                           \
    for (int kh = 0; kh < 2; ++kh)                                              \
        _Pragma("unroll")                                                       \
        for (int j = 0; j < 2; ++j)                                             \
            _Pragma("unroll")                                                   \
            for (int nt = 0; nt < 4; ++nt)                                      \
                acc[2*(Q)+j][nt] = __builtin_amdgcn_mfma_f32_16x16x32_bf16(     \
                    AF[j*2+kh], BF[nt][kh], acc[2*(Q)+j][nt], 0, 0, 0);         \
    __builtin_amdgcn_s_setprio(0);

    // One K-tile: compute from BC/af*, prefetch B(t+1)->BN, A one quadrant ahead.
#define TILE(BC, BN, kO)                                                        \
    LDAQ(af1, (kO), 1)          /* A for Q1 */                                  \
    LDBF(BN, (kO) + 1024, 0)                                                    \
    MFMAQ(0, af0, BC)                                                           \
    LDAQ(af0, (kO), 2)          /* A for Q2 */                                  \
    LDBF(BN, (kO) + 1024, 1)                                                    \
    MFMAQ(1, af1, BC)                                                           \
    LDAQ(af1, (kO), 3)          /* A for Q3 */                                  \
    LDBF(BN, (kO) + 1024, 2)                                                    \
    MFMAQ(2, af0, BC)                                                           \
    LDAQ(af0, (kO) + 1024, 0)   /* next tile's Q0 */                            \
    LDBF(BN, (kO) + 1024, 3)                                                    \
    MFMAQ(3, af1, BC)

    // prologue: tile 0 operands
    LDBF(bfA, 0, 0) LDBF(bfA, 0, 1) LDBF(bfA, 0, 2) LDBF(bfA, 0, 3)
    LDAQ(af0, 0, 0)

    int kO = 0;
#pragma unroll 1
    for (int p = 0; p < NT / 2; ++p) {
        TILE(bfA, bfB, kO)
        kO += 1024;
        TILE(bfB, bfA, kO)
        kO += 1024;
    }
#undef TILE
#undef LDAQ
#undef LDBF
#undef MFMAQ

    // ---- stage c_prev tile (256 rows x 64 f-cols) into padded LDS, coalesced ----
    float* cbuf = (float*)smem;                   // [256][CB_STR] = 68 KB
    const int fbase = n0 >> 2;
#pragma unroll
    for (int i = 0; i < 8; ++i) {
        const int q  = i * 512 + tid;             // 0..4095 float4-chunks
        const int r  = q >> 4;
        const int c4 = (q & 15) << 2;
        *(float4*)&cbuf[r * CB_STR + c4] =
            *(const float4*)&c_prev[(long)(m0 + r) * F_DIM + fbase + c4];
    }
    __syncthreads();

    // ---- fused epilogue (in-register 4x4 gate transpose, LDS-staged c/h) ----
    const int l3 = lane & 3;
    const int fl = (lane >> 2) & 3;
#pragma unroll
    for (int nt = 0; nt < 4; ++nt) {
        const int   gcol = n0 + wni * 64 + nt * 16 + lrow;
        const float bias = bperm[gcol];
#pragma unroll
        for (int mt = 0; mt < 8; ++mt) {
            float a0 = acc[mt][nt][0] + bias;
            float a1 = acc[mt][nt][1] + bias;
            float a2 = acc[mt][nt][2] + bias;
            float a3 = acc[mt][nt][3] + bias;
            // 4x4 transpose across lane quads: stage 1 (xor 1, reg bit 0)
            float s0 = (lane & 1) ? a0 : a1;
            float s1 = (lane & 1) ? a2 : a3;
            float t0 = __shfl_xor(s0, 1, 64);
            float t1 = __shfl_xor(s1, 1, 64);
            if (lane & 1) { a0 = t0; a2 = t1; } else { a1 = t0; a3 = t1; }
            // stage 2 (xor 2, reg bit 1)
            s0 = (lane & 2) ? a0 : a2;
            s1 = (lane & 2) ? a1 : a3;
            t0 = __shfl_xor(s0, 2, 64);
            t1 = __shfl_xor(s1, 2, 64);
            if (lane & 2) { a0 = t0; a1 = t1; } else { a2 = t0; a3 = t1; }
            // a0..a3 = pre-activation i,f,g,o for (local row, local f-col)
            const float iv = sigmoidf_fast(a0);
            const float fv = sigmoidf_fast(a1);
            const float gv = tanhf_fast(a2);
            const float ov = sigmoidf_fast(a3);
            const int lr = wmi * 128 + mt * 16 + quad * 4 + l3;   // 0..255
            const int lc = wni * 16 + nt * 4 + fl;                // 0..63
            const float cp = cbuf[lr * CB_STR + lc];
            const float cv = fv * cp + iv * gv;
            cbuf[lr * CB_STR + lc] = ov * tanhf_fast(cv);         // same-lane cell, no race
        }
    }
    __syncthreads();

    // ---- coalesced h store ----
#pragma unroll
    for (int i = 0; i < 8; ++i) {
        const int q  = i * 512 + tid;
        const int r  = q >> 4;
        const int c4 = (q & 15) << 2;
        *(float4*)&out[(long)(m0 + r) * F_DIM + fbase + c4] =
            *(const float4*)&cbuf[r * CB_STR + c4];
    }
}

// ---------------------------------------------------------------------------
// Inputs (setup_inputs order): behavior, h_prev, c_prev, Wh, Wx, b  (all fp32)
// Output: h (N_ROWS x F_DIM fp32)
// Workspace: A2 bf16 48 MB | W2 bf16 12 MB | b' 16 KB
// (tail prefetch may read up to 1 KB past W2 -> lands in bperm, in-bounds)
// ---------------------------------------------------------------------------
extern "C" void kernel_launch(void* const* d_in, const int* in_sizes, int n_in,
                              void* d_out, int out_size, void* d_ws, size_t ws_size,
                              hipStream_t stream) {
    const float* behavior = (const float*)d_in[0];
    const float* h_prev   = (const float*)d_in[1];
    const float* c_prev   = (const float*)d_in[2];
    const float* Wh       = (const float*)d_in[3];
    const float* Wx       = (const float*)d_in[4];
    const float* b        = (const float*)d_in[5];
    float* out = (float*)d_out;

    unsigned short* A2 = (unsigned short*)d_ws;
    unsigned short* W2 = A2 + (size_t)N_ROWS * K_DIM;
    float*       bperm = (float*)(W2 + (size_t)G_DIM * K_DIM);

    hipFuncSetAttribute(reinterpret_cast<const void*>(lstm_gemm),
                        hipFuncAttributeMaxDynamicSharedMemorySize, 69632);

    pack_all<<<N_ROWS + G_DIM, 192, 0, stream>>>(behavior, h_prev, Wh, Wx, b, A2, W2, bperm);
    lstm_gemm<<<dim3((N_ROWS / 256) * (G_DIM / 256)), 512, 69632, stream>>>(A2, W2, bperm, c_prev, out);
}